// Round 5
// baseline (1641.782 us; speedup 1.0000x reference)
//
#include <hip/hip_runtime.h>
#include <cstdint>
#include <cstddef>

#define HW 4096
#define NPQ 3844

typedef __attribute__((ext_vector_type(8))) short bf16x8;
typedef __attribute__((ext_vector_type(4))) float f32x4;
typedef unsigned short ushort;
typedef unsigned int uint;

__device__ __forceinline__ ushort f2bu(float f){
  uint u = __float_as_uint(f);
  uint r = (u + 0x7fffu + ((u >> 16) & 1u)) >> 16;
  return (ushort)r;
}
__device__ __forceinline__ uint umax2x16(uint a, uint b){
  uint ah = a >> 16, bh = b >> 16, al = a & 0xffffu, bl = b & 0xffffu;
  uint h = ah > bh ? ah : bh, l = al > bl ? al : bl;
  return (h << 16) | l;
}

// ---------------- feature matching (bit-identical numerics to round 3) ----------------

__global__ __launch_bounds__(256) void k_norm(const float* __restrict__ f,
                                              float* __restrict__ fn,
                                              float* __restrict__ spix){
  int pix = blockIdx.x*256 + threadIdx.x;
  if (pix >= HW) return;
  float s = 0.f;
  for (int c=0;c<256;c++){ float v = f[c*HW + pix]; s += v*v; }
  float n = fmaxf(sqrtf(s), 1e-12f);
  float s2 = 0.f;
  for (int c=0;c<256;c++){
    float v = f[c*HW + pix] / n;
    fn[c*HW + pix] = v;
    s2 += v*v;
  }
  spix[pix] = s2;
}

__global__ __launch_bounds__(256) void k_normpq(const float* __restrict__ s1,
                                                const float* __restrict__ s2,
                                                float* __restrict__ normP,
                                                float* __restrict__ normQ){
  int p = blockIdx.x*256 + threadIdx.x;
  if (p >= NPQ) return;
  int py = p/62, px = p - py*62;
  float a=0.f, b=0.f;
  for (int dy=0;dy<3;dy++)
    for (int dx=0;dx<3;dx++){
      int o = (py+dy)*64 + px+dx;
      a += s1[o]; b += s2[o];
    }
  normP[p] = sqrtf(a) + 1e-5f;
  normQ[p] = sqrtf(b) + 1e-5f;
}

// E[m][n] = sum_k A[k][m]*B[k][n]; per-element fmaf chain k=0..255 ascending
// (bit-identical to round 3). Scheduling: reg-prefetch double-buffer, b128 LDS,
// split j-fragment (tx*4 and 64+tx*4) for 2-way (free) LDS bank access.
__global__ __launch_bounds__(256) void k_gemm(const float* __restrict__ A,
                                              const float* __restrict__ B,
                                              float* __restrict__ E){
  __shared__ float As[16][132];
  __shared__ float Bs[16][132];
  const int m0 = blockIdx.y*128, n0 = blockIdx.x*128;
  const int tid = threadIdx.x;
  const int ty = tid>>4, tx = tid&15;
  const int f0 = tid*2;
  const int k0a = f0>>5,     c0a = (f0&31)<<2;
  const int k1a = (f0+1)>>5, c1a = ((f0+1)&31)<<2;

  float4 pa0 = *(const float4*)(A + (size_t)k0a*HW + m0 + c0a);
  float4 pa1 = *(const float4*)(A + (size_t)k1a*HW + m0 + c1a);
  float4 pb0 = *(const float4*)(B + (size_t)k0a*HW + n0 + c0a);
  float4 pb1 = *(const float4*)(B + (size_t)k1a*HW + n0 + c1a);

  float acc[8][8];
  #pragma unroll
  for (int i=0;i<8;i++)
    #pragma unroll
    for (int j=0;j<8;j++) acc[i][j]=0.f;

  for (int t=0;t<16;t++){
    __syncthreads();
    *(float4*)&As[k0a][c0a] = pa0;
    *(float4*)&As[k1a][c1a] = pa1;
    *(float4*)&Bs[k0a][c0a] = pb0;
    *(float4*)&Bs[k1a][c1a] = pb1;
    __syncthreads();
    if (t < 15){
      const float* An = A + (size_t)(t+1)*16*HW;
      const float* Bn = B + (size_t)(t+1)*16*HW;
      pa0 = *(const float4*)(An + (size_t)k0a*HW + m0 + c0a);
      pa1 = *(const float4*)(An + (size_t)k1a*HW + m0 + c1a);
      pb0 = *(const float4*)(Bn + (size_t)k0a*HW + n0 + c0a);
      pb1 = *(const float4*)(Bn + (size_t)k1a*HW + n0 + c1a);
    }
    #pragma unroll
    for (int k=0;k<16;k++){
      float4 a0 = *(const float4*)&As[k][ty*8];
      float4 a1 = *(const float4*)&As[k][ty*8+4];
      float4 b0 = *(const float4*)&Bs[k][tx*4];
      float4 b1 = *(const float4*)&Bs[k][64+tx*4];
      float a[8] = {a0.x,a0.y,a0.z,a0.w,a1.x,a1.y,a1.z,a1.w};
      float b[8] = {b0.x,b0.y,b0.z,b0.w,b1.x,b1.y,b1.z,b1.w};
      #pragma unroll
      for (int i=0;i<8;i++)
        #pragma unroll
        for (int j=0;j<8;j++) acc[i][j] = fmaf(a[i], b[j], acc[i][j]);
    }
  }
  #pragma unroll
  for (int i=0;i<8;i++){
    float4 v0 = make_float4(acc[i][0],acc[i][1],acc[i][2],acc[i][3]);
    float4 v1 = make_float4(acc[i][4],acc[i][5],acc[i][6],acc[i][7]);
    float* rowp = E + (size_t)(m0+ty*8+i)*HW + n0;
    *(float4*)(rowp + tx*4) = v0;
    *(float4*)(rowp + 64 + tx*4) = v1;
  }
}

// per patch P: max/argmax over Q of (sum of 9 shifted E entries)/normQ; /normP at end.
// Thread = 16 consecutive q in one row; float4 window loads; EXACT round-3 add order.
__global__ __launch_bounds__(256) void k_reduce(const float* __restrict__ E,
                                                const float* __restrict__ normP,
                                                const float* __restrict__ normQ,
                                                float* __restrict__ maxval,
                                                int* __restrict__ maxidx){
  const int p = blockIdx.x;
  const int py = p/62, px = p - py*62;
  const int t = threadIdx.x;
  float best = -3.0e38f; int bq = 1<<30;

  if (t < 248){
    const int qy = t >> 2, g = t & 3;
    const int qx0 = g*16;
    const int cnt = (g==3) ? 14 : 16;
    float s[16];
    #pragma unroll
    for (int j=0;j<16;j++) s[j]=0.f;
    #pragma unroll
    for (int dy=0;dy<3;dy++){
      const int cbase = (qy+dy)*64 + qx0;
      #pragma unroll
      for (int dx=0;dx<3;dx++){
        const float* row = E + (size_t)((py+dy)*64 + px+dx)*HW + cbase;
        float4 w0 = *(const float4*)(row);
        float4 w1 = *(const float4*)(row+4);
        float4 w2 = *(const float4*)(row+8);
        float4 w3 = *(const float4*)(row+12);
        float4 w4 = (g<3) ? *(const float4*)(row+16) : make_float4(0.f,0.f,0.f,0.f);
        float w[20] = {w0.x,w0.y,w0.z,w0.w, w1.x,w1.y,w1.z,w1.w,
                       w2.x,w2.y,w2.z,w2.w, w3.x,w3.y,w3.z,w3.w,
                       w4.x,w4.y,w4.z,w4.w};
        #pragma unroll
        for (int j=0;j<16;j++) s[j] += w[dx+j];
      }
    }
    const int qbase = qy*62 + qx0;
    for (int j=0;j<cnt;j++){
      float v = s[j] / normQ[qbase + j];
      if (v > best){ best = v; bq = qbase + j; }
    }
  }

  __shared__ float sv[256];
  __shared__ int si[256];
  sv[t] = best; si[t] = bq;
  __syncthreads();
  for (int off=128; off>0; off>>=1){
    if (t < off){
      float ov = sv[t+off]; int oi = si[t+off];
      float cv = sv[t];     int ci = si[t];
      if (ov > cv || (ov == cv && oi < ci)){ sv[t]=ov; si[t]=oi; }
    }
    __syncthreads();
  }
  if (t == 0){
    maxval[p] = sv[0] / normP[p];
    maxidx[p] = si[0];
  }
}

// ---------------- flow / sim outputs (unchanged) ----------------

__global__ __launch_bounds__(256) void k_flow3(const int* __restrict__ maxidx,
                                               const float* __restrict__ maxval,
                                               float* __restrict__ flow3ws,
                                               float* __restrict__ sim3ws,
                                               float* __restrict__ oflow,
                                               float* __restrict__ osim){
  int idx = blockIdx.x*256 + threadIdx.x;
  if (idx >= 4*HW) return;
  int b = idx >> 12, r = idx & 4095;
  int y = r >> 6, x = r & 63;
  float fx = 0.f, fy = 0.f;
  if (y < 62 && x < 62){
    int mi = maxidx[b*NPQ + y*62 + x];
    int qy = mi/62, qx = mi - qy*62;
    fx = (float)(qx - x);
    fy = (float)(qy - y);
  }
  flow3ws[idx*2] = fx; flow3ws[idx*2+1] = fy;
  oflow[idx*2] = fx; oflow[idx*2+1] = fy;
  float sv = 0.f;
  if (y >= 1 && y <= 62 && x >= 1 && x <= 62)
    sv = maxval[b*NPQ + (y-1)*62 + (x-1)];
  sim3ws[idx] = sv;
  osim[idx] = sv;
}

__global__ __launch_bounds__(256) void k_off3(const float* __restrict__ flow3ws,
                                              float* __restrict__ out){
  int idx = blockIdx.x*256 + threadIdx.x;
  if (idx >= 4*9*HW) return;
  int b = idx / (9*HW);
  int rem = idx - b*9*HW;
  int k = rem >> 12;
  int r = rem & 4095;
  int y = r >> 6, x = r & 63;
  int i = k/3, j = k - i*3;
  float fx = 0.f, fy = 0.f;
  if (y >= i && x >= j){
    int s = (b*HW + (y-i)*64 + (x-j))*2;
    fx = flow3ws[s]; fy = flow3ws[s+1];
  }
  out[idx*2] = fx; out[idx*2+1] = fy;
}

__global__ __launch_bounds__(256) void k_flowS(const float* __restrict__ flow3ws,
                                               const float* __restrict__ sim3ws,
                                               float* __restrict__ oflow,
                                               float* __restrict__ osim,
                                               int S, int N){
  int idx = blockIdx.x*256 + threadIdx.x;
  int tot = 4*N*N;
  if (idx >= tot) return;
  int b = idx/(N*N);
  int r = idx - b*N*N;
  int y = r/N, x = r - y*N;
  int s = b*HW + (y/S)*64 + (x/S);
  float fx = flow3ws[s*2] * (float)S;
  float fy = flow3ws[s*2+1] * (float)S;
  oflow[idx*2] = fx; oflow[idx*2+1] = fy;
  osim[idx] = sim3ws[s];
}

__global__ __launch_bounds__(256) void k_offS(const float* __restrict__ flow3ws,
                                              float* __restrict__ out,
                                              int S, int N){
  int idx = blockIdx.x*256 + threadIdx.x;
  int tot = 4*9*N*N;
  if (idx >= tot) return;
  int b = idx/(9*N*N);
  int rem = idx - b*9*N*N;
  int k = rem/(N*N);
  int r = rem - k*(N*N);
  int y = r/N, x = r - y*N;
  int i = k/3, j = k - i*3;
  float fx = 0.f, fy = 0.f;
  int sy = y - S*i, sx = x - S*j;
  if (sy >= 0 && sx >= 0){
    int s = (b*HW + (sy/S)*64 + (sx/S))*2;
    fx = flow3ws[s] * (float)S;
    fy = flow3ws[s+1] * (float)S;
  }
  out[idx*2] = fx; out[idx*2+1] = fy;
}

// ---------------- VGG ----------------

__global__ __launch_bounds__(256) void k_imgnorm(const float* __restrict__ img,
                                                 float* __restrict__ x0){
  int idx = blockIdx.x*256 + threadIdx.x;
  if (idx >= 3*65536) return;
  int c = idx >> 16;
  float mean = (c==0)?0.485f:((c==1)?0.456f:0.406f);
  float stdv = (c==0)?0.229f:((c==1)?0.224f:0.225f);
  x0[idx] = (img[idx] - mean) / stdv;
}

// weight transform: fp32 OIHW -> bf16 [tap][oc][ci]
__global__ __launch_bounds__(256) void k_wt(const float* __restrict__ w,
                                            ushort* __restrict__ wt,
                                            int Cout, int Cin){
  int idx = blockIdx.x*256 + threadIdx.x;
  int tot = Cout*Cin*9;
  if (idx >= tot) return;
  int o = idx / (Cin*9);
  int rem = idx - o*(Cin*9);
  int i = rem / 9;
  int tap = rem - i*9;
  wt[((size_t)tap*Cout + o)*Cin + i] = f2bu(w[idx]);
}

// direct fp32 conv for conv1_1 (Cin=3); writes fp32 CHW (d_out) + bf16 HWC (next stage)
__global__ __launch_bounds__(256) void k_conv(const float* __restrict__ in,
                                              const float* __restrict__ w,
                                              const float* __restrict__ bias,
                                              float* __restrict__ outf,
                                              ushort* __restrict__ outb,
                                              int Cin, int Cout, int H, int W){
  __shared__ float sIn[16][18][20];
  __shared__ float sW[8][16][9];
  const int tx = threadIdx.x & 15, ty = threadIdx.x >> 4;
  const int x0 = blockIdx.x*16, y0 = blockIdx.y*16;
  const int oc0 = blockIdx.z*8;
  float acc[8];
  #pragma unroll
  for (int o=0;o<8;o++) acc[o]=0.f;
  for (int c0=0; c0<Cin; c0+=16){
    int chunk = Cin - c0; if (chunk > 16) chunk = 16;
    for (int i = threadIdx.x; i < chunk*324; i += 256){
      int ci = i / 324;
      int rr = i - ci*324;
      int iy = rr / 18, ix = rr - iy*18;
      int gy = y0 + iy - 1, gx = x0 + ix - 1;
      float v = 0.f;
      if (gy >= 0 && gy < H && gx >= 0 && gx < W)
        v = in[(size_t)(c0+ci)*H*W + (size_t)gy*W + gx];
      sIn[ci][iy][ix] = v;
    }
    for (int i = threadIdx.x; i < 8*chunk*9; i += 256){
      int o = i / (chunk*9);
      int rr = i - o*chunk*9;
      int ci = rr / 9, t = rr - ci*9;
      sW[o][ci][t] = w[((size_t)(oc0+o)*Cin + c0+ci)*9 + t];
    }
    __syncthreads();
    for (int ci=0; ci<chunk; ci++){
      #pragma unroll
      for (int ky=0;ky<3;ky++){
        #pragma unroll
        for (int kx=0;kx<3;kx++){
          float v = sIn[ci][ty+ky][tx+kx];
          #pragma unroll
          for (int o=0;o<8;o++)
            acc[o] = fmaf(v, sW[o][ci][ky*3+kx], acc[o]);
        }
      }
    }
    __syncthreads();
  }
  #pragma unroll
  for (int o=0;o<8;o++){
    float rres = fmaxf(acc[o] + bias[oc0+o], 0.f);
    if (outf) outf[(size_t)(oc0+o)*H*W + (size_t)(y0+ty)*W + (x0+tx)] = rres;
    if (outb) outb[((size_t)(y0+ty)*W + (x0+tx))*(size_t)Cout + (oc0+o)] = f2bu(rres);
  }
}

// MFMA implicit-GEMM 3x3 SAME conv, bf16 in / fp32 acc.
__global__ __launch_bounds__(256) void k_conv_mfma(const ushort* __restrict__ X,
                                                   const ushort* __restrict__ Wt,
                                                   const float* __restrict__ bias,
                                                   ushort* __restrict__ outHWC,
                                                   float* __restrict__ outCHW,
                                                   int Cin, int Cout, int H, int W){
  extern __shared__ ushort smem[];
  const int CS = Cin + 8;
  ushort* sX = smem;                      // [10][18][CS]
  ushort* sW = smem + 10*18*CS;           // [64][CS]
  const int tid = threadIdx.x;
  const int wave = tid >> 6, lane = tid & 63;
  const int quad = lane >> 4, l16 = lane & 15;
  const int x0 = blockIdx.x * 16, y0 = blockIdx.y * 8, oc0 = blockIdx.z * 64;
  const int nci8 = Cin >> 3;
  const int c8s = (Cin == 128) ? 4 : 3;
  const int c8m = nci8 - 1;

  for (int i = tid; i < 180*nci8; i += 256){
    int c8 = i & c8m;
    int rest = i >> c8s;
    int px = rest % 18;
    int row = rest / 18;
    int gy = y0 - 1 + row, gx = x0 - 1 + px;
    uint4 v = make_uint4(0u,0u,0u,0u);
    if (gy >= 0 && gy < H && gx >= 0 && gx < W)
      v = *(const uint4*)(X + ((size_t)gy*W + gx)*Cin + c8*8);
    *(uint4*)(sX + (row*18 + px)*CS + c8*8) = v;
  }

  f32x4 acc[2][4];
  #pragma unroll
  for (int m=0;m<2;m++)
    #pragma unroll
    for (int r=0;r<4;r++) acc[m][r] = (f32x4){0.f,0.f,0.f,0.f};

  const int my = (wave>>1)*4;
  const int mo = (wave&1)*32;

  for (int tap = 0; tap < 9; tap++){
    int dy = tap/3 - 1, dx = tap - (tap/3)*3 - 1;
    __syncthreads();
    const ushort* wsrc = Wt + ((size_t)tap*Cout + oc0)*Cin;
    for (int i = tid; i < 64*nci8; i += 256){
      int c8 = i & c8m, o = i >> c8s;
      *(uint4*)(sW + o*CS + c8*8) = *(const uint4*)(wsrc + o*Cin + c8*8);
    }
    __syncthreads();
    for (int k0 = 0; k0 < Cin; k0 += 32){
      bf16x8 A0 = *(const bf16x8*)(sW + (mo + l16)*CS + k0 + quad*8);
      bf16x8 A1 = *(const bf16x8*)(sW + (mo + 16 + l16)*CS + k0 + quad*8);
      #pragma unroll
      for (int r = 0; r < 4; r++){
        bf16x8 B = *(const bf16x8*)(sX + ((1 + my + r + dy)*18 + (1 + l16 + dx))*CS + k0 + quad*8);
        acc[0][r] = __builtin_amdgcn_mfma_f32_16x16x32_bf16(A0, B, acc[0][r], 0, 0, 0);
        acc[1][r] = __builtin_amdgcn_mfma_f32_16x16x32_bf16(A1, B, acc[1][r], 0, 0, 0);
      }
    }
  }

  const int x = x0 + l16;
  #pragma unroll
  for (int m = 0; m < 2; m++){
    int ocb = oc0 + mo + m*16 + quad*4;
    float4 bv = *(const float4*)(bias + ocb);
    #pragma unroll
    for (int r = 0; r < 4; r++){
      int y = y0 + my + r;
      float v0 = fmaxf(acc[m][r][0] + bv.x, 0.f);
      float v1 = fmaxf(acc[m][r][1] + bv.y, 0.f);
      float v2 = fmaxf(acc[m][r][2] + bv.z, 0.f);
      float v3 = fmaxf(acc[m][r][3] + bv.w, 0.f);
      if (outHWC){
        uint lo = (uint)f2bu(v0) | ((uint)f2bu(v1) << 16);
        uint hi = (uint)f2bu(v2) | ((uint)f2bu(v3) << 16);
        // GLOBAL oc index — do not localize (round-4 bug: (ocb-oc0) collided
        // z-blocks on channels 0..63 and left 64..127 unwritten garbage)
        uint2* dst = (uint2*)(outHWC + ((size_t)y*W + x)*Cout + ocb);
        *dst = make_uint2(lo, hi);
      }
      if (outCHW){
        size_t base = (size_t)ocb*H*W + (size_t)y*W + x;
        outCHW[base]                 = v0;
        outCHW[base +   (size_t)H*W] = v1;
        outCHW[base + 2*(size_t)H*W] = v2;
        outCHW[base + 3*(size_t)H*W] = v3;
      }
    }
  }
}

__global__ __launch_bounds__(256) void k_pool_h(const ushort* __restrict__ in,
                                                ushort* __restrict__ out,
                                                int C, int Wo, int s){
  int idx = blockIdx.x*256 + threadIdx.x;
  int nc8 = C >> 3;
  if (idx >= Wo*nc8) return;
  int x = idx >> s;
  int c8 = idx & (nc8 - 1);
  int y = blockIdx.y;
  int Wi = 2*Wo;
  const ushort* p = in + ((size_t)(2*y)*Wi + 2*x)*C + c8*8;
  uint4 a = *(const uint4*)p;
  uint4 b = *(const uint4*)(p + C);
  uint4 c = *(const uint4*)(p + (size_t)Wi*C);
  uint4 d = *(const uint4*)(p + (size_t)Wi*C + C);
  uint4 m;
  m.x = umax2x16(umax2x16(a.x,b.x), umax2x16(c.x,d.x));
  m.y = umax2x16(umax2x16(a.y,b.y), umax2x16(c.y,d.y));
  m.z = umax2x16(umax2x16(a.z,b.z), umax2x16(c.z,d.z));
  m.w = umax2x16(umax2x16(a.w,b.w), umax2x16(c.w,d.w));
  *(uint4*)(out + ((size_t)y*Wo + x)*C + c8*8) = m;
}

// ---------------- launch ----------------

extern "C" void kernel_launch(void* const* d_in, const int* in_sizes, int n_in,
                              void* d_out, int out_size, void* d_ws, size_t ws_size,
                              hipStream_t stream){
  const float* f1  = (const float*)d_in[0];
  const float* f2  = (const float*)d_in[1];
  const float* img = (const float*)d_in[2];
  const float* w11 = (const float*)d_in[3];  const float* b11 = (const float*)d_in[4];
  const float* w12 = (const float*)d_in[5];  const float* b12 = (const float*)d_in[6];
  const float* w21 = (const float*)d_in[7];  const float* b21 = (const float*)d_in[8];
  const float* w22 = (const float*)d_in[9];  const float* b22 = (const float*)d_in[10];
  const float* w31 = (const float*)d_in[11]; const float* b31 = (const float*)d_in[12];
  float* out = (float*)d_out;

  float* F = (float*)d_ws;
  float* E    = F;                      // 16,777,216 floats (64 MB), reused
  float* f1n  = F + 16777216;
  float* f2n  = F + 17825792;
  float* s1   = F + 18874368;
  float* s2   = F + 18878464;
  float* nP   = F + 18882560;
  float* nQ   = F + 18886656;
  float* mval = F + 18890752;
  int*   midx = (int*)(F + 18907136);
  float* fl3  = F + 18923520;
  float* sm3  = F + 18956288;

  ushort* wt1  = (ushort*)(F + 16777216);
  ushort* wt2a = (ushort*)(F + 16795648);
  ushort* wt2b = (ushort*)(F + 16832512);
  ushort* wt3  = (ushort*)(F + 16906240);

  float*  x0  = E;
  ushort* t1u = (ushort*)(E + 196608);
  ushort* t2u = (ushort*)(E + 2293760);
  ushort* p1u = (ushort*)(E + 4390912);
  ushort* t3u = (ushort*)(E + 4915200);
  ushort* t4u = (ushort*)(E + 5963776);
  ushort* p2u = (ushort*)(E + 7012352);

  const size_t O_OFF3 = 0, O_OFF2 = 294912, O_OFF1 = 1474560;
  const size_t O_FLOW3 = 6193152, O_FLOW2 = 6225920, O_FLOW1 = 6356992;
  const size_t O_SIM3 = 6881280, O_SIM2 = 6897664, O_SIM1 = 6963200;
  const size_t O_R1 = 7225344, O_R2 = 24002560, O_R3 = 32391168;

  for (int b=0;b<4;b++){
    const float* f1b = f1 + (size_t)b*256*HW;
    const float* f2b2 = f2 + (size_t)b*256*HW;
    k_norm<<<16,256,0,stream>>>(f1b, f1n, s1);
    k_norm<<<16,256,0,stream>>>(f2b2, f2n, s2);
    k_normpq<<<16,256,0,stream>>>(s1, s2, nP, nQ);
    k_gemm<<<dim3(32,32),256,0,stream>>>(f1n, f2n, E);
    k_reduce<<<NPQ,256,0,stream>>>(E, nP, nQ, mval + b*NPQ, midx + b*NPQ);
  }
  k_flow3<<<64,256,0,stream>>>(midx, mval, fl3, sm3, out+O_FLOW3, out+O_SIM3);
  k_off3<<<576,256,0,stream>>>(fl3, out+O_OFF3);
  k_flowS<<<256,256,0,stream>>>(fl3, sm3, out+O_FLOW2, out+O_SIM2, 2, 128);
  k_offS<<<2304,256,0,stream>>>(fl3, out+O_OFF2, 2, 128);
  k_flowS<<<1024,256,0,stream>>>(fl3, sm3, out+O_FLOW1, out+O_SIM1, 4, 256);
  k_offS<<<9216,256,0,stream>>>(fl3, out+O_OFF1, 4, 256);

  k_wt<<<144,256,0,stream>>>(w12, wt1, 64, 64);
  k_wt<<<288,256,0,stream>>>(w21, wt2a, 128, 64);
  k_wt<<<576,256,0,stream>>>(w22, wt2b, 128, 128);
  k_wt<<<1152,256,0,stream>>>(w31, wt3, 256, 128);

  const int smem64  = (180*72  + 64*72)  * 2;
  const int smem128 = (180*136 + 64*136) * 2;

  for (int b=0;b<4;b++){
    k_imgnorm<<<768,256,0,stream>>>(img + (size_t)b*3*65536, x0);
    k_conv<<<dim3(16,16,8),256,0,stream>>>(x0, w11, b11,
        out + O_R1 + (size_t)b*64*65536, t1u, 3, 64, 256, 256);
    k_conv_mfma<<<dim3(16,32,1),256,smem64,stream>>>(t1u, wt1, b12, t2u, nullptr, 64, 64, 256, 256);
    k_pool_h<<<dim3(4,128),256,0,stream>>>(t2u, p1u, 64, 128, 3);
    k_conv_mfma<<<dim3(8,16,2),256,smem64,stream>>>(p1u, wt2a, b21, t3u,
        out + O_R2 + (size_t)b*128*16384, 64, 128, 128, 128);
    k_conv_mfma<<<dim3(8,16,2),256,smem128,stream>>>(t3u, wt2b, b22, t4u, nullptr, 128, 128, 128, 128);
    k_pool_h<<<dim3(4,64),256,0,stream>>>(t4u, p2u, 128, 64, 4);
    k_conv_mfma<<<dim3(4,8,4),256,smem128,stream>>>(p2u, wt3, b31, nullptr,
        out + O_R3 + (size_t)b*256*4096, 128, 256, 64, 64);
  }
}

// Round 6
// 1205.619 us; speedup vs baseline: 1.3618x; 1.3618x over previous
//
#include <hip/hip_runtime.h>
#include <cstdint>
#include <cstddef>

#define HW 4096
#define NPQ 3844

typedef __attribute__((ext_vector_type(8))) short bf16x8;
typedef __attribute__((ext_vector_type(4))) float f32x4;
typedef unsigned short ushort;
typedef unsigned int uint;

__device__ __forceinline__ ushort f2bu(float f){
  uint u = __float_as_uint(f);
  uint r = (u + 0x7fffu + ((u >> 16) & 1u)) >> 16;
  return (ushort)r;
}
__device__ __forceinline__ uint umax2x16(uint a, uint b){
  uint ah = a >> 16, bh = b >> 16, al = a & 0xffffu, bl = b & 0xffffu;
  uint h = ah > bh ? ah : bh, l = al > bl ? al : bl;
  return (h << 16) | l;
}

// ---------------- feature matching ----------------

// per-pixel channel L2 normalize; block = 16 px x 16 channel-groups, LDS tree reduce.
// (sum order differs from the old sequential version by ~1 ulp on n — below the
// demonstrated ~2e-6 argmax tie margin.)
__global__ __launch_bounds__(256) void k_norm(const float* __restrict__ f,
                                              float* __restrict__ fn,
                                              float* __restrict__ spix){
  __shared__ float red[16][17];
  const int px = threadIdx.x & 15, cg = threadIdx.x >> 4;
  const int pix = blockIdx.x*16 + px;
  float s = 0.f;
  #pragma unroll
  for (int i=0;i<16;i++){ float v = f[(cg*16+i)*HW + pix]; s += v*v; }
  red[cg][px] = s; __syncthreads();
  for (int off=8; off>0; off>>=1){
    if (cg < off) red[cg][px] += red[cg+off][px];
    __syncthreads();
  }
  float n = fmaxf(sqrtf(red[0][px]), 1e-12f);
  float s2 = 0.f;
  #pragma unroll
  for (int i=0;i<16;i++){
    float v = f[(cg*16+i)*HW + pix] / n;   // keep fdiv (matches reference rounding)
    fn[(cg*16+i)*HW + pix] = v;
    s2 += v*v;
  }
  __syncthreads();
  red[cg][px] = s2; __syncthreads();
  for (int off=8; off>0; off>>=1){
    if (cg < off) red[cg][px] += red[cg+off][px];
    __syncthreads();
  }
  if (cg == 0) spix[pix] = red[0][px];
}

__global__ __launch_bounds__(256) void k_normpq(const float* __restrict__ s1,
                                                const float* __restrict__ s2,
                                                float* __restrict__ normP,
                                                float* __restrict__ normQ){
  int p = blockIdx.x*256 + threadIdx.x;
  if (p >= NPQ) return;
  int py = p/62, px = p - py*62;
  float a=0.f, b=0.f;
  for (int dy=0;dy<3;dy++)
    for (int dx=0;dx<3;dx++){
      int o = (py+dy)*64 + px+dx;
      a += s1[o]; b += s2[o];
    }
  normP[p] = sqrtf(a) + 1e-5f;
  normQ[p] = sqrtf(b) + 1e-5f;
}

// E[m][n] = sum_k A[k][m]*B[k][n]; per-element fmaf chain k=0..255 ascending
// (bit-identical to rounds 3/5). 128m x 256n tile, 8x16 acc/thread:
// 128 fmaf per 6 ds_read_b128, half the barriers per FLOP vs 128x128.
__global__ __launch_bounds__(256) void k_gemm(const float* __restrict__ A,
                                              const float* __restrict__ B,
                                              float* __restrict__ E){
  __shared__ float As[16][132];
  __shared__ float Bs[16][264];
  const int m0 = blockIdx.y*128, n0 = blockIdx.x*256;
  const int tid = threadIdx.x;
  const int ty = tid>>4, tx = tid&15;
  // staging map: thread -> As[ty][tx*8..+7], Bs[ty][tx*16..+15]
  const int ac = tx*8, bc = tx*16;

  float4 pa0 = *(const float4*)(A + (size_t)ty*HW + m0 + ac);
  float4 pa1 = *(const float4*)(A + (size_t)ty*HW + m0 + ac + 4);
  float4 pb0 = *(const float4*)(B + (size_t)ty*HW + n0 + bc);
  float4 pb1 = *(const float4*)(B + (size_t)ty*HW + n0 + bc + 4);
  float4 pb2 = *(const float4*)(B + (size_t)ty*HW + n0 + bc + 8);
  float4 pb3 = *(const float4*)(B + (size_t)ty*HW + n0 + bc + 12);

  float acc[8][16];
  #pragma unroll
  for (int i=0;i<8;i++)
    #pragma unroll
    for (int j=0;j<16;j++) acc[i][j]=0.f;

  for (int t=0;t<16;t++){
    __syncthreads();
    *(float4*)&As[ty][ac]    = pa0;
    *(float4*)&As[ty][ac+4]  = pa1;
    *(float4*)&Bs[ty][bc]    = pb0;
    *(float4*)&Bs[ty][bc+4]  = pb1;
    *(float4*)&Bs[ty][bc+8]  = pb2;
    *(float4*)&Bs[ty][bc+12] = pb3;
    __syncthreads();
    if (t < 15){
      const float* An = A + (size_t)(t+1)*16*HW;
      const float* Bn = B + (size_t)(t+1)*16*HW;
      pa0 = *(const float4*)(An + (size_t)ty*HW + m0 + ac);
      pa1 = *(const float4*)(An + (size_t)ty*HW + m0 + ac + 4);
      pb0 = *(const float4*)(Bn + (size_t)ty*HW + n0 + bc);
      pb1 = *(const float4*)(Bn + (size_t)ty*HW + n0 + bc + 4);
      pb2 = *(const float4*)(Bn + (size_t)ty*HW + n0 + bc + 8);
      pb3 = *(const float4*)(Bn + (size_t)ty*HW + n0 + bc + 12);
    }
    #pragma unroll
    for (int k=0;k<16;k++){
      float4 a0 = *(const float4*)&As[k][ty*8];
      float4 a1 = *(const float4*)&As[k][ty*8+4];
      float4 b0 = *(const float4*)&Bs[k][tx*4];
      float4 b1 = *(const float4*)&Bs[k][64+tx*4];
      float4 b2 = *(const float4*)&Bs[k][128+tx*4];
      float4 b3 = *(const float4*)&Bs[k][192+tx*4];
      float a[8] = {a0.x,a0.y,a0.z,a0.w,a1.x,a1.y,a1.z,a1.w};
      float b[16] = {b0.x,b0.y,b0.z,b0.w,b1.x,b1.y,b1.z,b1.w,
                     b2.x,b2.y,b2.z,b2.w,b3.x,b3.y,b3.z,b3.w};
      #pragma unroll
      for (int i=0;i<8;i++)
        #pragma unroll
        for (int j=0;j<16;j++) acc[i][j] = fmaf(a[i], b[j], acc[i][j]);
    }
  }
  #pragma unroll
  for (int i=0;i<8;i++){
    float* rowp = E + (size_t)(m0+ty*8+i)*HW + n0;
    *(float4*)(rowp + tx*4)       = make_float4(acc[i][0], acc[i][1], acc[i][2], acc[i][3]);
    *(float4*)(rowp + 64 + tx*4)  = make_float4(acc[i][4], acc[i][5], acc[i][6], acc[i][7]);
    *(float4*)(rowp + 128 + tx*4) = make_float4(acc[i][8], acc[i][9], acc[i][10], acc[i][11]);
    *(float4*)(rowp + 192 + tx*4) = make_float4(acc[i][12], acc[i][13], acc[i][14], acc[i][15]);
  }
}

// per patch P: max/argmax over Q (unchanged from round 5)
__global__ __launch_bounds__(256) void k_reduce(const float* __restrict__ E,
                                                const float* __restrict__ normP,
                                                const float* __restrict__ normQ,
                                                float* __restrict__ maxval,
                                                int* __restrict__ maxidx){
  const int p = blockIdx.x;
  const int py = p/62, px = p - py*62;
  const int t = threadIdx.x;
  float best = -3.0e38f; int bq = 1<<30;

  if (t < 248){
    const int qy = t >> 2, g = t & 3;
    const int qx0 = g*16;
    const int cnt = (g==3) ? 14 : 16;
    float s[16];
    #pragma unroll
    for (int j=0;j<16;j++) s[j]=0.f;
    #pragma unroll
    for (int dy=0;dy<3;dy++){
      const int cbase = (qy+dy)*64 + qx0;
      #pragma unroll
      for (int dx=0;dx<3;dx++){
        const float* row = E + (size_t)((py+dy)*64 + px+dx)*HW + cbase;
        float4 w0 = *(const float4*)(row);
        float4 w1 = *(const float4*)(row+4);
        float4 w2 = *(const float4*)(row+8);
        float4 w3 = *(const float4*)(row+12);
        float4 w4 = (g<3) ? *(const float4*)(row+16) : make_float4(0.f,0.f,0.f,0.f);
        float w[20] = {w0.x,w0.y,w0.z,w0.w, w1.x,w1.y,w1.z,w1.w,
                       w2.x,w2.y,w2.z,w2.w, w3.x,w3.y,w3.z,w3.w,
                       w4.x,w4.y,w4.z,w4.w};
        #pragma unroll
        for (int j=0;j<16;j++) s[j] += w[dx+j];
      }
    }
    const int qbase = qy*62 + qx0;
    for (int j=0;j<cnt;j++){
      float v = s[j] / normQ[qbase + j];
      if (v > best){ best = v; bq = qbase + j; }
    }
  }

  __shared__ float sv[256];
  __shared__ int si[256];
  sv[t] = best; si[t] = bq;
  __syncthreads();
  for (int off=128; off>0; off>>=1){
    if (t < off){
      float ov = sv[t+off]; int oi = si[t+off];
      float cv = sv[t];     int ci = si[t];
      if (ov > cv || (ov == cv && oi < ci)){ sv[t]=ov; si[t]=oi; }
    }
    __syncthreads();
  }
  if (t == 0){
    maxval[p] = sv[0] / normP[p];
    maxidx[p] = si[0];
  }
}

// ---------------- flow / sim outputs (unchanged) ----------------

__global__ __launch_bounds__(256) void k_flow3(const int* __restrict__ maxidx,
                                               const float* __restrict__ maxval,
                                               float* __restrict__ flow3ws,
                                               float* __restrict__ sim3ws,
                                               float* __restrict__ oflow,
                                               float* __restrict__ osim){
  int idx = blockIdx.x*256 + threadIdx.x;
  if (idx >= 4*HW) return;
  int b = idx >> 12, r = idx & 4095;
  int y = r >> 6, x = r & 63;
  float fx = 0.f, fy = 0.f;
  if (y < 62 && x < 62){
    int mi = maxidx[b*NPQ + y*62 + x];
    int qy = mi/62, qx = mi - qy*62;
    fx = (float)(qx - x);
    fy = (float)(qy - y);
  }
  flow3ws[idx*2] = fx; flow3ws[idx*2+1] = fy;
  oflow[idx*2] = fx; oflow[idx*2+1] = fy;
  float sv = 0.f;
  if (y >= 1 && y <= 62 && x >= 1 && x <= 62)
    sv = maxval[b*NPQ + (y-1)*62 + (x-1)];
  sim3ws[idx] = sv;
  osim[idx] = sv;
}

__global__ __launch_bounds__(256) void k_off3(const float* __restrict__ flow3ws,
                                              float* __restrict__ out){
  int idx = blockIdx.x*256 + threadIdx.x;
  if (idx >= 4*9*HW) return;
  int b = idx / (9*HW);
  int rem = idx - b*9*HW;
  int k = rem >> 12;
  int r = rem & 4095;
  int y = r >> 6, x = r & 63;
  int i = k/3, j = k - i*3;
  float fx = 0.f, fy = 0.f;
  if (y >= i && x >= j){
    int s = (b*HW + (y-i)*64 + (x-j))*2;
    fx = flow3ws[s]; fy = flow3ws[s+1];
  }
  out[idx*2] = fx; out[idx*2+1] = fy;
}

__global__ __launch_bounds__(256) void k_flowS(const float* __restrict__ flow3ws,
                                               const float* __restrict__ sim3ws,
                                               float* __restrict__ oflow,
                                               float* __restrict__ osim,
                                               int S, int N){
  int idx = blockIdx.x*256 + threadIdx.x;
  int tot = 4*N*N;
  if (idx >= tot) return;
  int b = idx/(N*N);
  int r = idx - b*N*N;
  int y = r/N, x = r - y*N;
  int s = b*HW + (y/S)*64 + (x/S);
  float fx = flow3ws[s*2] * (float)S;
  float fy = flow3ws[s*2+1] * (float)S;
  oflow[idx*2] = fx; oflow[idx*2+1] = fy;
  osim[idx] = sim3ws[s];
}

__global__ __launch_bounds__(256) void k_offS(const float* __restrict__ flow3ws,
                                              float* __restrict__ out,
                                              int S, int N){
  int idx = blockIdx.x*256 + threadIdx.x;
  int tot = 4*9*N*N;
  if (idx >= tot) return;
  int b = idx/(9*N*N);
  int rem = idx - b*9*N*N;
  int k = rem/(N*N);
  int r = rem - k*(N*N);
  int y = r/N, x = r - y*N;
  int i = k/3, j = k - i*3;
  float fx = 0.f, fy = 0.f;
  int sy = y - S*i, sx = x - S*j;
  if (sy >= 0 && sx >= 0){
    int s = (b*HW + (sy/S)*64 + (sx/S))*2;
    fx = flow3ws[s] * (float)S;
    fy = flow3ws[s+1] * (float)S;
  }
  out[idx*2] = fx; out[idx*2+1] = fy;
}

// ---------------- VGG ----------------

// weight transform: fp32 OIHW -> bf16 [tap][oc][ci]
__global__ __launch_bounds__(256) void k_wt(const float* __restrict__ w,
                                            ushort* __restrict__ wt,
                                            int Cout, int Cin){
  int idx = blockIdx.x*256 + threadIdx.x;
  int tot = Cout*Cin*9;
  if (idx >= tot) return;
  int o = idx / (Cin*9);
  int rem = idx - o*(Cin*9);
  int i = rem / 9;
  int tap = rem - i*9;
  wt[((size_t)tap*Cout + o)*Cin + i] = f2bu(w[idx]);
}

// conv1_1: direct fp32, Cin=3, H=W=256, fused imagenet normalize; batched via z
// (z: b = z>>3, oc-group = z&7). Writes fp32 CHW (d_out) + bf16 HWC (next stage).
__global__ __launch_bounds__(256) void k_conv1(const float* __restrict__ img,
                                               const float* __restrict__ w,
                                               const float* __restrict__ bias,
                                               float* __restrict__ outf,
                                               ushort* __restrict__ outb){
  __shared__ float sIn[3][18][20];
  __shared__ float sW[8][3][9];
  const int tx = threadIdx.x & 15, ty = threadIdx.x >> 4;
  const int x0 = blockIdx.x*16, y0 = blockIdx.y*16;
  const int b = blockIdx.z >> 3;
  const int oc0 = (blockIdx.z & 7)*8;
  const float MEAN[3] = {0.485f,0.456f,0.406f};
  const float STDV[3] = {0.229f,0.224f,0.225f};
  const float* in = img + (size_t)b*3*65536;
  for (int i = threadIdx.x; i < 3*324; i += 256){
    int ci = i / 324;
    int rr = i - ci*324;
    int iy = rr / 18, ix = rr - iy*18;
    int gy = y0 + iy - 1, gx = x0 + ix - 1;
    float v = 0.f;
    if (gy >= 0 && gy < 256 && gx >= 0 && gx < 256)
      v = (in[ci*65536 + gy*256 + gx] - MEAN[ci]) / STDV[ci];
    sIn[ci][iy][ix] = v;
  }
  if (threadIdx.x < 216){
    int o = threadIdx.x / 27;
    int rr = threadIdx.x - o*27;
    int ci = rr / 9, t = rr - ci*9;
    sW[o][ci][t] = w[((oc0+o)*3 + ci)*9 + t];
  }
  __syncthreads();
  float acc[8] = {0.f,0.f,0.f,0.f,0.f,0.f,0.f,0.f};
  for (int ci=0; ci<3; ci++){
    #pragma unroll
    for (int ky=0;ky<3;ky++){
      #pragma unroll
      for (int kx=0;kx<3;kx++){
        float v = sIn[ci][ty+ky][tx+kx];
        #pragma unroll
        for (int o=0;o<8;o++)
          acc[o] = fmaf(v, sW[o][ci][ky*3+kx], acc[o]);
      }
    }
  }
  #pragma unroll
  for (int o=0;o<8;o++){
    float r = fmaxf(acc[o] + bias[oc0+o], 0.f);
    outf[(size_t)b*4194304 + (size_t)(oc0+o)*65536 + (size_t)(y0+ty)*256 + (x0+tx)] = r;
    outb[(size_t)b*4194304 + ((size_t)(y0+ty)*256 + (x0+tx))*64 + (oc0+o)] = f2bu(r);
  }
}

// MFMA implicit-GEMM 3x3 SAME conv, bf16 in / fp32 acc; batched via z
// (z = b*zDiv + oc-tile; per-batch pointer strides in elements).
__global__ __launch_bounds__(256) void k_conv_mfma(const ushort* __restrict__ X,
                                                   const ushort* __restrict__ Wt,
                                                   const float* __restrict__ bias,
                                                   ushort* __restrict__ outHWC,
                                                   float* __restrict__ outCHW,
                                                   int Cin, int Cout, int H, int W,
                                                   int zDiv, size_t xStride,
                                                   size_t hwcStride, size_t chwStride){
  extern __shared__ ushort smem[];
  const int CS = Cin + 8;
  ushort* sX = smem;                      // [10][18][CS]
  ushort* sW = smem + 10*18*CS;           // [64][CS]
  const int tid = threadIdx.x;
  const int wave = tid >> 6, lane = tid & 63;
  const int quad = lane >> 4, l16 = lane & 15;
  const int bz = blockIdx.z / zDiv;
  const int zo = blockIdx.z - bz*zDiv;
  const int x0 = blockIdx.x * 16, y0 = blockIdx.y * 8, oc0 = zo * 64;
  X += (size_t)bz * xStride;
  if (outHWC) outHWC += (size_t)bz * hwcStride;
  if (outCHW) outCHW += (size_t)bz * chwStride;
  const int nci8 = Cin >> 3;
  const int c8s = (Cin == 128) ? 4 : 3;
  const int c8m = nci8 - 1;

  for (int i = tid; i < 180*nci8; i += 256){
    int c8 = i & c8m;
    int rest = i >> c8s;
    int px = rest % 18;
    int row = rest / 18;
    int gy = y0 - 1 + row, gx = x0 - 1 + px;
    uint4 v = make_uint4(0u,0u,0u,0u);
    if (gy >= 0 && gy < H && gx >= 0 && gx < W)
      v = *(const uint4*)(X + ((size_t)gy*W + gx)*Cin + c8*8);
    *(uint4*)(sX + (row*18 + px)*CS + c8*8) = v;
  }

  f32x4 acc[2][4];
  #pragma unroll
  for (int m=0;m<2;m++)
    #pragma unroll
    for (int r=0;r<4;r++) acc[m][r] = (f32x4){0.f,0.f,0.f,0.f};

  const int my = (wave>>1)*4;
  const int mo = (wave&1)*32;

  for (int tap = 0; tap < 9; tap++){
    int dy = tap/3 - 1, dx = tap - (tap/3)*3 - 1;
    __syncthreads();
    const ushort* wsrc = Wt + ((size_t)tap*Cout + oc0)*Cin;
    for (int i = tid; i < 64*nci8; i += 256){
      int c8 = i & c8m, o = i >> c8s;
      *(uint4*)(sW + o*CS + c8*8) = *(const uint4*)(wsrc + o*Cin + c8*8);
    }
    __syncthreads();
    for (int k0 = 0; k0 < Cin; k0 += 32){
      bf16x8 A0 = *(const bf16x8*)(sW + (mo + l16)*CS + k0 + quad*8);
      bf16x8 A1 = *(const bf16x8*)(sW + (mo + 16 + l16)*CS + k0 + quad*8);
      #pragma unroll
      for (int r = 0; r < 4; r++){
        bf16x8 B = *(const bf16x8*)(sX + ((1 + my + r + dy)*18 + (1 + l16 + dx))*CS + k0 + quad*8);
        acc[0][r] = __builtin_amdgcn_mfma_f32_16x16x32_bf16(A0, B, acc[0][r], 0, 0, 0);
        acc[1][r] = __builtin_amdgcn_mfma_f32_16x16x32_bf16(A1, B, acc[1][r], 0, 0, 0);
      }
    }
  }

  const int x = x0 + l16;
  #pragma unroll
  for (int m = 0; m < 2; m++){
    int ocb = oc0 + mo + m*16 + quad*4;
    float4 bv = *(const float4*)(bias + ocb);
    #pragma unroll
    for (int r = 0; r < 4; r++){
      int y = y0 + my + r;
      float v0 = fmaxf(acc[m][r][0] + bv.x, 0.f);
      float v1 = fmaxf(acc[m][r][1] + bv.y, 0.f);
      float v2 = fmaxf(acc[m][r][2] + bv.z, 0.f);
      float v3 = fmaxf(acc[m][r][3] + bv.w, 0.f);
      if (outHWC){
        uint lo = (uint)f2bu(v0) | ((uint)f2bu(v1) << 16);
        uint hi = (uint)f2bu(v2) | ((uint)f2bu(v3) << 16);
        // GLOBAL oc index (round-4 bug: localizing collided z-tiles)
        uint2* dst = (uint2*)(outHWC + ((size_t)y*W + x)*Cout + ocb);
        *dst = make_uint2(lo, hi);
      }
      if (outCHW){
        size_t base = (size_t)ocb*H*W + (size_t)y*W + x;
        outCHW[base]                 = v0;
        outCHW[base +   (size_t)H*W] = v1;
        outCHW[base + 2*(size_t)H*W] = v2;
        outCHW[base + 3*(size_t)H*W] = v3;
      }
    }
  }
}

// 2x2 max-pool on HWC bf16 (post-relu, non-negative -> u16 compare); batched via z
__global__ __launch_bounds__(256) void k_pool_h(const ushort* __restrict__ in,
                                                ushort* __restrict__ out,
                                                int C, int Wo, int s,
                                                size_t inStride, size_t outStride){
  in  += (size_t)blockIdx.z * inStride;
  out += (size_t)blockIdx.z * outStride;
  int idx = blockIdx.x*256 + threadIdx.x;
  int nc8 = C >> 3;
  if (idx >= Wo*nc8) return;
  int x = idx >> s;
  int c8 = idx & (nc8 - 1);
  int y = blockIdx.y;
  int Wi = 2*Wo;
  const ushort* p = in + ((size_t)(2*y)*Wi + 2*x)*C + c8*8;
  uint4 a = *(const uint4*)p;
  uint4 b = *(const uint4*)(p + C);
  uint4 c = *(const uint4*)(p + (size_t)Wi*C);
  uint4 d = *(const uint4*)(p + (size_t)Wi*C + C);
  uint4 m;
  m.x = umax2x16(umax2x16(a.x,b.x), umax2x16(c.x,d.x));
  m.y = umax2x16(umax2x16(a.y,b.y), umax2x16(c.y,d.y));
  m.z = umax2x16(umax2x16(a.z,b.z), umax2x16(c.z,d.z));
  m.w = umax2x16(umax2x16(a.w,b.w), umax2x16(c.w,d.w));
  *(uint4*)(out + ((size_t)y*Wo + x)*C + c8*8) = m;
}

// ---------------- launch ----------------

extern "C" void kernel_launch(void* const* d_in, const int* in_sizes, int n_in,
                              void* d_out, int out_size, void* d_ws, size_t ws_size,
                              hipStream_t stream){
  const float* f1  = (const float*)d_in[0];
  const float* f2  = (const float*)d_in[1];
  const float* img = (const float*)d_in[2];
  const float* w11 = (const float*)d_in[3];  const float* b11 = (const float*)d_in[4];
  const float* w12 = (const float*)d_in[5];  const float* b12 = (const float*)d_in[6];
  const float* w21 = (const float*)d_in[7];  const float* b21 = (const float*)d_in[8];
  const float* w22 = (const float*)d_in[9];  const float* b22 = (const float*)d_in[10];
  const float* w31 = (const float*)d_in[11]; const float* b31 = (const float*)d_in[12];
  float* out = (float*)d_out;

  float* F = (float*)d_ws;
  float* E    = F;                      // 16,777,216 floats (64 MB), reused
  float* f1n  = F + 16777216;
  float* f2n  = F + 17825792;
  float* s1   = F + 18874368;
  float* s2   = F + 18878464;
  float* nP   = F + 18882560;
  float* nQ   = F + 18886656;
  float* mval = F + 18890752;
  int*   midx = (int*)(F + 18907136);
  float* fl3  = F + 18923520;
  float* sm3  = F + 18956288;

  ushort* wt1  = (ushort*)(F + 16777216);   // aliases f1n (dead after matching)
  ushort* wt2a = (ushort*)(F + 16795648);
  ushort* wt2b = (ushort*)(F + 16832512);
  ushort* wt3  = (ushort*)(F + 16906240);

  // VGG activations alias the E region (64 MB), all 4 batches concurrently:
  // t1(32MB)@0 + t2(32MB)@32MB; later stages overwrite dead buffers.
  ushort* EU  = (ushort*)E;
  ushort* t1a = EU;                 // 4 x 4,194,304
  ushort* t2a = EU + 16777216;      // 4 x 4,194,304
  ushort* p1a = EU;                 // 4 x 1,048,576  (t1 dead)
  ushort* t3a = EU + 4194304;       // 4 x 2,097,152
  ushort* t4a = EU + 16777216;      // 4 x 2,097,152  (t2 dead)
  ushort* p2a = EU;                 // 4 x   524,288  (p1 dead)

  const size_t O_OFF3 = 0, O_OFF2 = 294912, O_OFF1 = 1474560;
  const size_t O_FLOW3 = 6193152, O_FLOW2 = 6225920, O_FLOW1 = 6356992;
  const size_t O_SIM3 = 6881280, O_SIM2 = 6897664, O_SIM1 = 6963200;
  const size_t O_R1 = 7225344, O_R2 = 24002560, O_R3 = 32391168;

  for (int b=0;b<4;b++){
    const float* f1b = f1 + (size_t)b*256*HW;
    const float* f2b2 = f2 + (size_t)b*256*HW;
    k_norm<<<256,256,0,stream>>>(f1b, f1n, s1);
    k_norm<<<256,256,0,stream>>>(f2b2, f2n, s2);
    k_normpq<<<16,256,0,stream>>>(s1, s2, nP, nQ);
    k_gemm<<<dim3(16,32),256,0,stream>>>(f1n, f2n, E);
    k_reduce<<<NPQ,256,0,stream>>>(E, nP, nQ, mval + b*NPQ, midx + b*NPQ);
  }
  k_flow3<<<64,256,0,stream>>>(midx, mval, fl3, sm3, out+O_FLOW3, out+O_SIM3);
  k_off3<<<576,256,0,stream>>>(fl3, out+O_OFF3);
  k_flowS<<<256,256,0,stream>>>(fl3, sm3, out+O_FLOW2, out+O_SIM2, 2, 128);
  k_offS<<<2304,256,0,stream>>>(fl3, out+O_OFF2, 2, 128);
  k_flowS<<<1024,256,0,stream>>>(fl3, sm3, out+O_FLOW1, out+O_SIM1, 4, 256);
  k_offS<<<9216,256,0,stream>>>(fl3, out+O_OFF1, 4, 256);

  k_wt<<<144,256,0,stream>>>(w12, wt1, 64, 64);
  k_wt<<<288,256,0,stream>>>(w21, wt2a, 128, 64);
  k_wt<<<576,256,0,stream>>>(w22, wt2b, 128, 128);
  k_wt<<<1152,256,0,stream>>>(w31, wt3, 256, 128);

  const int smem64  = (180*72  + 64*72)  * 2;
  const int smem128 = (180*136 + 64*136) * 2;

  // batched VGG (grid.z carries batch)
  k_conv1<<<dim3(16,16,32),256,0,stream>>>(img, w11, b11, out + O_R1, t1a);
  k_conv_mfma<<<dim3(16,32,4),256,smem64,stream>>>(t1a, wt1, b12, t2a, nullptr,
      64, 64, 256, 256, 1, 4194304, 4194304, 0);
  k_pool_h<<<dim3(4,128,4),256,0,stream>>>(t2a, p1a, 64, 128, 3, 4194304, 1048576);
  k_conv_mfma<<<dim3(8,16,8),256,smem64,stream>>>(p1a, wt2a, b21, t3a, out + O_R2,
      64, 128, 128, 128, 2, 1048576, 2097152, 2097152);
  k_conv_mfma<<<dim3(8,16,8),256,smem128,stream>>>(t3a, wt2b, b22, t4a, nullptr,
      128, 128, 128, 128, 2, 2097152, 2097152, 0);
  k_pool_h<<<dim3(4,64,4),256,0,stream>>>(t4a, p2a, 128, 64, 4, 2097152, 524288);
  k_conv_mfma<<<dim3(4,8,16),256,smem128,stream>>>(p2a, wt3, b31, nullptr, out + O_R3,
      128, 256, 64, 64, 4, 524288, 0, 1048576);
}